// Round 13
// baseline (280.033 us; speedup 1.0000x reference)
//
#include <hip/hip_runtime.h>
#include <hip/hip_bf16.h>

#define Hh    128
#define NINc  384
#define KN    48
#define FFd   512
#define NNODE 8192
#define EGRID 768           // 3 blocks/CU, grid-stride over nodes

typedef __attribute__((ext_vector_type(8))) short short8v;
typedef __attribute__((ext_vector_type(4))) float f32x4;

__device__ __forceinline__ short f2bf1(float f){
  union { __hip_bfloat16 h; short s; } c; c.h = __float2bfloat16(f);
  return c.s;
}
__device__ __forceinline__ unsigned pk_bf16(float lo, float hi){
  union { __hip_bfloat162 h; unsigned u; } c;
  c.h = __float22bfloat162_rn(make_float2(lo, hi));
  return c.u;
}

// 0.5x(1+tanh(t)) == x*sigmoid(2t); max dev from erf-GELU ~3e-4
__device__ __forceinline__ float gelu_f(float x){
  float t = 0.7978845608028654f * x * (1.0f + 0.044715f * x * x);
  float e = __expf(2.0f * t);
  return x * (1.0f - 1.0f / (e + 1.0f));
}

// LDS-publish barrier WITHOUT vmem drain (prefetch loads stay in flight)
__device__ __forceinline__ void bar_lds(){
  asm volatile("s_waitcnt lgkmcnt(0)\n\ts_barrier" ::: "memory");
}

// ---------------- weight prep ----------------
// w1vT/w3T: [128 out][128 in] bf16. w1p/w2p fragment-packed:
// [ntile][ks][lane][8] bf16 -> one wave frag = 1 contiguous KB.
__global__ void prep_weights(const float* __restrict__ W1, const float* __restrict__ W2,
                             const float* __restrict__ W3, const float* __restrict__ Win,
                             const float* __restrict__ Wout,
                             short* __restrict__ w1vT, short* __restrict__ w1p,
                             short* __restrict__ w2p,  short* __restrict__ w3T,
                             short* __restrict__ winT, short* __restrict__ woutT)
{
  int i = blockIdx.x * 256 + threadIdx.x;
  if (i < 16384){ int n = i / 128, k = i % 128; w1vT[i] = f2bf1(W1[k*128 + n]); return; }
  i -= 16384;
  if (i < 49152){ // w1p: n<8, ks<12
    int n = i / 6144, r = i % 6144;
    int ks = r / 512, r2 = r % 512;
    int lane = r2 / 8, j = r2 % 8;
    int qq = lane >> 4, arow = lane & 15;
    w1p[i] = f2bf1(W1[(128 + ks*32 + qq*8 + j)*128 + n*16 + arow]); return;
  }
  i -= 49152;
  if (i < 16384){ // w2p: n<8, ks<4
    int n = i / 2048, r = i % 2048;
    int ks = r / 512, r2 = r % 512;
    int lane = r2 / 8, j = r2 % 8;
    int qq = lane >> 4, arow = lane & 15;
    w2p[i] = f2bf1(W2[(ks*32 + qq*8 + j)*128 + n*16 + arow]); return;
  }
  i -= 16384;
  if (i < 16384){ int n = i / 128, k = i % 128; w3T[i] = f2bf1(W3[k*128 + n]); return; }
  i -= 16384;
  if (i < 65536){ int n = i / 128, k = i % 128; winT[i] = f2bf1(Win[k*512 + n]); return; }
  i -= 65536;
  if (i < 65536){ int n = i / 512, k = i % 512; woutT[i] = f2bf1(Wout[k*128 + n]); return; }
}

// ---------------- node_part = h_V @ W1[:128,:] + b1  (256 blocks, 32 rows) ----
__global__ __launch_bounds__(256,4) void np_kernel(
    const float* __restrict__ hV, const short* __restrict__ w1vT,
    const float* __restrict__ b1, float* __restrict__ npart)
{
  const int row0 = blockIdx.x * 32;
  const int tid = threadIdx.x, lane = tid & 63, wv = tid >> 6;
  __shared__ __attribute__((aligned(16))) short Xs[32][Hh + 8];

  const float4* src = (const float4*)(hV + (size_t)row0 * Hh);
  #pragma unroll
  for (int j = 0; j < 4; ++j){
    int idx = tid + 256*j;
    int r = idx >> 5, c4 = idx & 31;
    float4 v = src[idx];
    *(uint2*)&Xs[r][c4*4] = make_uint2(pk_bf16(v.x,v.y), pk_bf16(v.z,v.w));
  }
  __syncthreads();

  const int arow = lane & 15, kgrp = (lane >> 4) * 8;
  const int col0 = wv * 32, ccol = lane & 15, crow0 = (lane >> 4) * 4;

  f32x4 acc[2][2];
  #pragma unroll
  for (int m = 0; m < 2; ++m) for (int n = 0; n < 2; ++n) acc[m][n] = (f32x4){0.f,0.f,0.f,0.f};

  const short8v* Bw = (const short8v*)w1vT;
  #pragma unroll
  for (int ks = 0; ks < 4; ++ks){
    int kb = ks*32 + kgrp;
    short8v b0 = Bw[(col0 + arow)*16      + (kb >> 3)];
    short8v b1f = Bw[(col0 + 16 + arow)*16 + (kb >> 3)];
    #pragma unroll
    for (int m = 0; m < 2; ++m){
      short8v a = *(const short8v*)&Xs[m*16 + arow][kb];
      acc[m][0] = __builtin_amdgcn_mfma_f32_16x16x32_bf16(a, b0,  acc[m][0], 0,0,0);
      acc[m][1] = __builtin_amdgcn_mfma_f32_16x16x32_bf16(a, b1f, acc[m][1], 0,0,0);
    }
  }
  #pragma unroll
  for (int m = 0; m < 2; ++m) for (int n = 0; n < 2; ++n){
    int colg = col0 + n*16 + ccol;
    float bb = b1[colg];
    #pragma unroll
    for (int r = 0; r < 4; ++r)
      npart[(size_t)(row0 + m*16 + crow0 + r)*Hh + colg] = acc[m][n][r] + bb;
  }
}

// ---------------- edge MLP: cross-node chunk ring pipeline ----------------
// 768 semi-persistent blocks (3/CU), grid-stride ~11 nodes each. Et chunks
// are consumed by G1C(c) immediately, so node t+1's chunks stage IN PLACE
// during node t's tail phases -> loads outstanding in every phase. 5 phases,
// 4 lgkm-only barriers per node. Collapsed-G3 epilogue emits masked sum s.
__global__ __launch_bounds__(256,3) void edge_kernel(
    const float* __restrict__ hE,
    const float* __restrict__ maskA, const float* __restrict__ npart,
    const short* __restrict__ w1p, const short* __restrict__ w2p,
    const float* __restrict__ b2,
    float* __restrict__ sbuf, float* __restrict__ smaskbuf)
{
  const int tid = threadIdx.x, lane = tid & 63, wv = tid >> 6;   // wv 0..3
  const int e = lane & 15, q = lane >> 4;
  const int n0 = wv * 32;

  __shared__ __attribute__((aligned(16))) short Et[KN][NINc + 8];  // 37632B
  __shared__ __attribute__((aligned(16))) short M1[KN][136];       // 13056B

  const float4 b2v0 = *(const float4*)(b2 + n0 + 4*q);
  const float4 b2v1 = *(const float4*)(b2 + n0 + 16 + 4*q);
  const short8v* B1  = (const short8v*)w1p;
  const short8v* B2f = (const short8v*)w2p;
  const f32x4 Z = (f32x4){0.f,0.f,0.f,0.f};

  float4 pf[6];
  f32x4 a00, a10, a20, a01, a11, a21;

  auto LOADC = [&](int nn, int c){
    if (nn >= NNODE) return;                 // tail guard (pf stays stale; harmless)
    const float4* src = (const float4*)(hE + (size_t)nn * (KN*NINc));
    #pragma unroll
    for (int j = 0; j < 6; ++j){
      int idx = tid + 256*j;                 // < 1536
      int r = idx >> 5, c4 = idx & 31;
      pf[j] = src[r*96 + c*32 + c4];
    }
  };
  auto STOREC = [&](int c){
    #pragma unroll
    for (int j = 0; j < 6; ++j){
      int idx = tid + 256*j;
      int r = idx >> 5, c4 = idx & 31;
      *(uint2*)&Et[r][c*128 + c4*4] =
        make_uint2(pk_bf16(pf[j].x, pf[j].y), pk_bf16(pf[j].z, pf[j].w));
    }
  };
  auto G1C = [&](int c){
    #pragma unroll
    for (int kk = 0; kk < 4; ++kk){
      int ks = c*4 + kk;
      short8v f0 = B1[((2*wv  )*12 + ks)*64 + lane];
      short8v f1 = B1[((2*wv+1)*12 + ks)*64 + lane];
      int kb = ks*32 + q*8;
      short8v t0 = *(const short8v*)&Et[e][kb];
      short8v t1 = *(const short8v*)&Et[16 + e][kb];
      short8v t2 = *(const short8v*)&Et[32 + e][kb];
      a00 = __builtin_amdgcn_mfma_f32_16x16x32_bf16(f0, t0, a00, 0,0,0);
      a10 = __builtin_amdgcn_mfma_f32_16x16x32_bf16(f0, t1, a10, 0,0,0);
      a20 = __builtin_amdgcn_mfma_f32_16x16x32_bf16(f0, t2, a20, 0,0,0);
      a01 = __builtin_amdgcn_mfma_f32_16x16x32_bf16(f1, t0, a01, 0,0,0);
      a11 = __builtin_amdgcn_mfma_f32_16x16x32_bf16(f1, t1, a11, 0,0,0);
      a21 = __builtin_amdgcn_mfma_f32_16x16x32_bf16(f1, t2, a21, 0,0,0);
    }
  };

  // prologue: first node's chunk0 staged, chunk1 loads outstanding
  LOADC(blockIdx.x, 0);
  STOREC(0);
  LOADC(blockIdx.x, 1);
  bar_lds();

  for (int node = blockIdx.x; node < NNODE; node += EGRID){
    const int nxt = node + EGRID;

    // per-node invariants (issued now; counted waits at use in phases 4/5)
    const float4 npv0 = *(const float4*)(npart + (size_t)node*Hh + n0 + 4*q);
    const float4 npv1 = *(const float4*)(npart + (size_t)node*Hh + n0 + 16 + 4*q);
    const float mk0 = maskA[node*KN + e];
    const float mk1 = maskA[node*KN + 16 + e];
    const float mk2 = maskA[node*KN + 32 + e];

    a00 = Z; a10 = Z; a20 = Z; a01 = Z; a11 = Z; a21 = Z;

    // phase1: compute c0 | publish c1 | fetch c2
    G1C(0); STOREC(1); LOADC(node, 2); bar_lds();
    // phase2: compute c1 | publish c2 | fetch next node's c0
    G1C(1); STOREC(2); LOADC(nxt, 0);  bar_lds();
    // phase3: compute c2 | publish next c0 (in-place, c0 dead) | fetch next c1
    G1C(2); STOREC(0); LOADC(nxt, 1);  bar_lds();

    // phase4: M1 = gelu(G1 + np)
    {
      #define WR_M(ACC, ET, COLB, BV)  { short4 s;                  \
        s.x = f2bf1(gelu_f(ACC[0] + BV.x));                         \
        s.y = f2bf1(gelu_f(ACC[1] + BV.y));                         \
        s.z = f2bf1(gelu_f(ACC[2] + BV.z));                         \
        s.w = f2bf1(gelu_f(ACC[3] + BV.w));                         \
        *(short4*)&M1[16*ET + e][COLB + 4*q] = s; }
      WR_M(a00, 0, n0,      npv0)  WR_M(a10, 1, n0,      npv0)
      WR_M(a20, 2, n0,      npv0)  WR_M(a01, 0, n0 + 16, npv1)
      WR_M(a11, 1, n0 + 16, npv1)  WR_M(a21, 2, n0 + 16, npv1)
      #undef WR_M
    }
    bar_lds();

    // phase5: G2 + collapsed-G3 epilogue (next node's c1 loads still in flight)
    {
      f32x4 c00=Z, c10=Z, c20=Z, c01=Z, c11=Z, c21=Z;
      #pragma unroll
      for (int ks = 0; ks < 4; ++ks){
        short8v f0 = B2f[((2*wv  )*4 + ks)*64 + lane];
        short8v f1 = B2f[((2*wv+1)*4 + ks)*64 + lane];
        int kb = ks*32 + q*8;
        short8v t0 = *(const short8v*)&M1[e][kb];
        short8v t1 = *(const short8v*)&M1[16 + e][kb];
        short8v t2 = *(const short8v*)&M1[32 + e][kb];
        c00 = __builtin_amdgcn_mfma_f32_16x16x32_bf16(f0, t0, c00, 0,0,0);
        c10 = __builtin_amdgcn_mfma_f32_16x16x32_bf16(f0, t1, c10, 0,0,0);
        c20 = __builtin_amdgcn_mfma_f32_16x16x32_bf16(f0, t2, c20, 0,0,0);
        c01 = __builtin_amdgcn_mfma_f32_16x16x32_bf16(f1, t0, c01, 0,0,0);
        c11 = __builtin_amdgcn_mfma_f32_16x16x32_bf16(f1, t1, c11, 0,0,0);
        c21 = __builtin_amdgcn_mfma_f32_16x16x32_bf16(f1, t2, c21, 0,0,0);
      }
      float sv0[4], sv1[4];
      #pragma unroll
      for (int r = 0; r < 4; ++r){
        sv0[r] = gelu_f(c00[r] + b2v0[r])*mk0 + gelu_f(c10[r] + b2v0[r])*mk1
               + gelu_f(c20[r] + b2v0[r])*mk2;
        sv1[r] = gelu_f(c01[r] + b2v1[r])*mk0 + gelu_f(c11[r] + b2v1[r])*mk1
               + gelu_f(c21[r] + b2v1[r])*mk2;
      }
      float m3 = mk0 + mk1 + mk2;
      #pragma unroll
      for (int s = 1; s <= 8; s <<= 1){
        #pragma unroll
        for (int r = 0; r < 4; ++r){
          sv0[r] += __shfl_xor(sv0[r], s);
          sv1[r] += __shfl_xor(sv1[r], s);
        }
        m3 += __shfl_xor(m3, s);
      }
      if (e == 0){
        *(float4*)(sbuf + (size_t)node*Hh + n0 + 4*q) =
            make_float4(sv0[0], sv0[1], sv0[2], sv0[3]);
        *(float4*)(sbuf + (size_t)node*Hh + n0 + 16 + 4*q) =
            make_float4(sv1[0], sv1[1], sv1[2], sv1[3]);
      }
      if (tid == 0) smaskbuf[node] = m3;
    }
    // no trailing barrier: next iter's phase1 bar protects M1 overwrite,
    // and Et c0/c1 publishes happened at phase2/3 bars above.
  }
}

// ---------------- fused: h = hV + (S@W3 + b3*sm)/30 -> LN1 -> FFN -> LN2 -> mask ----
__global__ __launch_bounds__(256,2) void ffn2_kernel(
    const float* __restrict__ hV, const float* __restrict__ sbuf,
    const float* __restrict__ smaskbuf, const short* __restrict__ w3T,
    const float* __restrict__ b3,
    const float* __restrict__ ln1g, const float* __restrict__ ln1b,
    const short* __restrict__ winT, const float* __restrict__ bin,
    const short* __restrict__ woutT, const float* __restrict__ bout,
    const float* __restrict__ ln2g, const float* __restrict__ ln2b,
    const float* __restrict__ maskV, float* __restrict__ out)
{
  const int row0 = blockIdx.x * 32;
  const int tid = threadIdx.x, lane = tid & 63, wv = tid >> 6;
  __shared__ __attribute__((aligned(16))) short Xs[32][Hh + 8];
  __shared__ __attribute__((aligned(16))) float Rs[32][Hh + 4];
  __shared__ __attribute__((aligned(16))) short Hs[32][FFd + 8];
  __shared__ float smS[32];

  const int arow = lane & 15, kgrp = (lane >> 4) * 8;
  const int ccol = lane & 15, crow0 = (lane >> 4) * 4;

  // stage S -> Xs (bf16), smask
  {
    const float4* src = (const float4*)(sbuf + (size_t)row0 * Hh);
    #pragma unroll
    for (int j = 0; j < 4; ++j){
      int idx = tid + 256*j;
      int r = idx >> 5, c4 = idx & 31;
      float4 v = src[idx];
      *(uint2*)&Xs[r][c4*4] = make_uint2(pk_bf16(v.x,v.y), pk_bf16(v.z,v.w));
    }
    if (tid < 32) smS[tid] = smaskbuf[row0 + tid];
  }
  __syncthreads();

  // dh GEMM: Rs = hV + (Xs@W3 + b3*sm)/30
  {
    f32x4 acc[2][2];
    #pragma unroll
    for (int m = 0; m < 2; ++m) for (int n = 0; n < 2; ++n) acc[m][n] = (f32x4){0.f,0.f,0.f,0.f};
    const short8v* Bw = (const short8v*)w3T;
    const int col0 = wv * 32;
    #pragma unroll
    for (int ks = 0; ks < 4; ++ks){
      int kb = ks*32 + kgrp;
      short8v b0 = Bw[(col0 + arow)*16      + (kb >> 3)];
      short8v b1f = Bw[(col0 + 16 + arow)*16 + (kb >> 3)];
      #pragma unroll
      for (int m = 0; m < 2; ++m){
        short8v a = *(const short8v*)&Xs[m*16 + arow][kb];
        acc[m][0] = __builtin_amdgcn_mfma_f32_16x16x32_bf16(a, b0,  acc[m][0], 0,0,0);
        acc[m][1] = __builtin_amdgcn_mfma_f32_16x16x32_bf16(a, b1f, acc[m][1], 0,0,0);
      }
    }
    #pragma unroll
    for (int m = 0; m < 2; ++m) for (int n = 0; n < 2; ++n){
      int colg = col0 + n*16 + ccol;
      float bb = b3[colg];
      #pragma unroll
      for (int r = 0; r < 4; ++r){
        int rl = m*16 + crow0 + r;
        Rs[rl][colg] = hV[(size_t)(row0 + rl)*Hh + colg]
                     + (acc[m][n][r] + bb*smS[rl]) * (1.0f/30.0f);
      }
    }
  }
  __syncthreads();

  // LN1 in place on Rs (each position owned by one thread); Xs = bf16(LN1)
  {
    int r = tid >> 3, cb = (tid & 7) * 16;
    float xv[16];
    #pragma unroll
    for (int j = 0; j < 16; ++j) xv[j] = Rs[r][cb + j];
    float sum = 0.f, sq = 0.f;
    #pragma unroll
    for (int j = 0; j < 16; ++j){ sum += xv[j]; sq += xv[j]*xv[j]; }
    #pragma unroll
    for (int d = 1; d < 8; d <<= 1){ sum += __shfl_xor(sum, d); sq += __shfl_xor(sq, d); }
    float mu = sum * (1.0f/128.0f);
    float var = sq * (1.0f/128.0f) - mu*mu;
    float rstd = rsqrtf(var + 1e-5f);
    #pragma unroll
    for (int j = 0; j < 16; ++j){
      int c = cb + j;
      float xn = (xv[j] - mu) * rstd * ln1g[c] + ln1b[c];
      Xs[r][c] = f2bf1(xn);
      Rs[r][c] = xn;          // residual
    }
  }
  __syncthreads();

  // GEMM-in: [32x128] @ WinT -> gelu -> Hs[32x512]
  {
    f32x4 acc[2][8];
    #pragma unroll
    for (int m = 0; m < 2; ++m) for (int n = 0; n < 8; ++n) acc[m][n] = (f32x4){0.f,0.f,0.f,0.f};
    const short8v* Bw = (const short8v*)winT;
    #pragma unroll
    for (int ks = 0; ks < 4; ++ks){
      int kb = ks*32 + kgrp;
      short8v a0 = *(const short8v*)&Xs[arow][kb];
      short8v a1 = *(const short8v*)&Xs[16 + arow][kb];
      #pragma unroll
      for (int n = 0; n < 8; ++n){
        short8v b = Bw[(wv*128 + n*16 + arow)*16 + (kb >> 3)];
        acc[0][n] = __builtin_amdgcn_mfma_f32_16x16x32_bf16(a0,b,acc[0][n],0,0,0);
        acc[1][n] = __builtin_amdgcn_mfma_f32_16x16x32_bf16(a1,b,acc[1][n],0,0,0);
      }
    }
    #pragma unroll
    for (int m = 0; m < 2; ++m) for (int n = 0; n < 8; ++n){
      int colg = wv*128 + n*16 + ccol;
      float bb = bin[colg];
      #pragma unroll
      for (int r = 0; r < 4; ++r)
        Hs[m*16 + crow0 + r][colg] = f2bf1(gelu_f(acc[m][n][r] + bb));
    }
  }
  __syncthreads();

  // GEMM-out: [32x512] @ WoutT -> + bout + resid -> Rs (pre-LN2)
  {
    f32x4 acc[2][2];
    #pragma unroll
    for (int m = 0; m < 2; ++m) for (int n = 0; n < 2; ++n) acc[m][n] = (f32x4){0.f,0.f,0.f,0.f};
    const short8v* Bw = (const short8v*)woutT;
    #pragma unroll
    for (int ks = 0; ks < 16; ++ks){
      int kb = ks*32 + kgrp;
      short8v a0 = *(const short8v*)&Hs[arow][kb];
      short8v a1 = *(const short8v*)&Hs[16 + arow][kb];
      short8v b0 = Bw[(wv*32 + arow)*64      + (kb >> 3)];
      short8v b1f = Bw[(wv*32 + 16 + arow)*64 + (kb >> 3)];
      acc[0][0] = __builtin_amdgcn_mfma_f32_16x16x32_bf16(a0,b0, acc[0][0],0,0,0);
      acc[1][0] = __builtin_amdgcn_mfma_f32_16x16x32_bf16(a1,b0, acc[1][0],0,0,0);
      acc[0][1] = __builtin_amdgcn_mfma_f32_16x16x32_bf16(a0,b1f,acc[0][1],0,0,0);
      acc[1][1] = __builtin_amdgcn_mfma_f32_16x16x32_bf16(a1,b1f,acc[1][1],0,0,0);
    }
    #pragma unroll
    for (int m = 0; m < 2; ++m) for (int n = 0; n < 2; ++n){
      int colg = wv*32 + n*16 + ccol;
      float bb = bout[colg];
      #pragma unroll
      for (int r = 0; r < 4; ++r){
        int rr = m*16 + crow0 + r;
        Rs[rr][colg] = Rs[rr][colg] + acc[m][n][r] + bb;
      }
    }
  }
  __syncthreads();

  // LN2 + mask + store
  {
    int r = tid >> 3, cb = (tid & 7) * 16;
    float xv[16];
    #pragma unroll
    for (int j = 0; j < 16; ++j) xv[j] = Rs[r][cb + j];
    float sum = 0.f, sq = 0.f;
    #pragma unroll
    for (int j = 0; j < 16; ++j){ sum += xv[j]; sq += xv[j]*xv[j]; }
    #pragma unroll
    for (int d = 1; d < 8; d <<= 1){ sum += __shfl_xor(sum, d); sq += __shfl_xor(sq, d); }
    float mu = sum * (1.0f/128.0f);
    float var = sq * (1.0f/128.0f) - mu*mu;
    float rstd = rsqrtf(var + 1e-5f);
    float mv = maskV[row0 + r];
    float* op = out + (size_t)(row0 + r)*Hh + cb;
    #pragma unroll
    for (int j = 0; j < 4; ++j){
      float4 o;
      o.x = ((xv[j*4+0] - mu)*rstd*ln2g[cb+j*4+0] + ln2b[cb+j*4+0]) * mv;
      o.y = ((xv[j*4+1] - mu)*rstd*ln2g[cb+j*4+1] + ln2b[cb+j*4+1]) * mv;
      o.z = ((xv[j*4+2] - mu)*rstd*ln2g[cb+j*4+2] + ln2b[cb+j*4+2]) * mv;
      o.w = ((xv[j*4+3] - mu)*rstd*ln2g[cb+j*4+3] + ln2b[cb+j*4+3]) * mv;
      ((float4*)op)[j] = o;
    }
  }
}

extern "C" void kernel_launch(void* const* d_in, const int* in_sizes, int n_in,
                              void* d_out, int out_size, void* d_ws, size_t ws_size,
                              hipStream_t stream)
{
  const float* hV    = (const float*)d_in[0];
  const float* hE    = (const float*)d_in[1];
  const float* maskV = (const float*)d_in[2];
  const float* maskA = (const float*)d_in[3];
  const float* W1w   = (const float*)d_in[4];
  const float* W1b   = (const float*)d_in[5];
  const float* W2w   = (const float*)d_in[6];
  const float* W2b   = (const float*)d_in[7];
  const float* W3w   = (const float*)d_in[8];
  const float* W3b   = (const float*)d_in[9];
  const float* Winw  = (const float*)d_in[10];
  const float* Winb  = (const float*)d_in[11];
  const float* Woutw = (const float*)d_in[12];
  const float* Woutb = (const float*)d_in[13];
  const float* l1g   = (const float*)d_in[14];
  const float* l1b   = (const float*)d_in[15];
  const float* l2g   = (const float*)d_in[16];
  const float* l2b   = (const float*)d_in[17];

  char* ws = (char*)d_ws;
  size_t off = 0;
  float* npart = (float*)(ws + off); off += (size_t)NNODE * Hh * 4;
  float* sbuf  = (float*)(ws + off); off += (size_t)NNODE * Hh * 4;
  float* smbuf = (float*)(ws + off); off += (size_t)NNODE * 4;
  short* w1vT  = (short*)(ws + off); off += 16384*2;
  short* w1p   = (short*)(ws + off); off += 49152*2;
  short* w2p   = (short*)(ws + off); off += 16384*2;
  short* w3T   = (short*)(ws + off); off += 16384*2;
  short* winT  = (short*)(ws + off); off += 65536*2;
  short* woutT = (short*)(ws + off); off += 65536*2;
  if (ws_size < off) return;

  prep_weights<<<896, 256, 0, stream>>>(W1w, W2w, W3w, Winw, Woutw,
                                        w1vT, w1p, w2p, w3T, winT, woutT);
  np_kernel<<<NNODE/32, 256, 0, stream>>>(hV, w1vT, W1b, npart);
  edge_kernel<<<EGRID, 256, 0, stream>>>(hE, maskA, npart,
                                         w1p, w2p, W2b, sbuf, smbuf);
  ffn2_kernel<<<NNODE/32, 256, 0, stream>>>(hV, sbuf, smbuf, w3T, W3b,
                                            l1g, l1b, winT, Winb, woutT, Woutb,
                                            l2g, l2b, maskV, (float*)d_out);
}

// Round 14
// 188.659 us; speedup vs baseline: 1.4843x; 1.4843x over previous
//
#include <hip/hip_runtime.h>
#include <hip/hip_bf16.h>

#define Hh    128
#define NINc  384
#define KN    48
#define FFd   512
#define NNODE 8192

typedef __attribute__((ext_vector_type(8))) short short8v;
typedef __attribute__((ext_vector_type(4))) float f32x4;

__device__ __forceinline__ short f2bf1(float f){
  union { __hip_bfloat16 h; short s; } c; c.h = __float2bfloat16(f);
  return c.s;
}
__device__ __forceinline__ unsigned pk_bf16(float lo, float hi){
  union { __hip_bfloat162 h; unsigned u; } c;
  c.h = __float22bfloat162_rn(make_float2(lo, hi));
  return c.u;
}

// 0.5x(1+tanh(t)) == x*sigmoid(2t); max dev from erf-GELU ~3e-4
__device__ __forceinline__ float gelu_f(float x){
  float t = 0.7978845608028654f * x * (1.0f + 0.044715f * x * x);
  float e = __expf(2.0f * t);
  return x * (1.0f - 1.0f / (e + 1.0f));
}

// LDS-publish barrier WITHOUT vmem drain (prefetch loads stay in flight)
__device__ __forceinline__ void bar_lds(){
  asm volatile("s_waitcnt lgkmcnt(0)\n\ts_barrier" ::: "memory");
}

// ---------------- weight prep ----------------
// w1vT/w3T: [128 out][128 in] bf16. w1p/w2p fragment-packed:
// [ntile][ks][lane][8] bf16 -> one wave frag = 1 contiguous KB.
__global__ void prep_weights(const float* __restrict__ W1, const float* __restrict__ W2,
                             const float* __restrict__ W3, const float* __restrict__ Win,
                             const float* __restrict__ Wout,
                             short* __restrict__ w1vT, short* __restrict__ w1p,
                             short* __restrict__ w2p,  short* __restrict__ w3T,
                             short* __restrict__ winT, short* __restrict__ woutT)
{
  int i = blockIdx.x * 256 + threadIdx.x;
  if (i < 16384){ int n = i / 128, k = i % 128; w1vT[i] = f2bf1(W1[k*128 + n]); return; }
  i -= 16384;
  if (i < 49152){ // w1p: n<8, ks<12
    int n = i / 6144, r = i % 6144;
    int ks = r / 512, r2 = r % 512;
    int lane = r2 / 8, j = r2 % 8;
    int qq = lane >> 4, arow = lane & 15;
    w1p[i] = f2bf1(W1[(128 + ks*32 + qq*8 + j)*128 + n*16 + arow]); return;
  }
  i -= 49152;
  if (i < 16384){ // w2p: n<8, ks<4
    int n = i / 2048, r = i % 2048;
    int ks = r / 512, r2 = r % 512;
    int lane = r2 / 8, j = r2 % 8;
    int qq = lane >> 4, arow = lane & 15;
    w2p[i] = f2bf1(W2[(ks*32 + qq*8 + j)*128 + n*16 + arow]); return;
  }
  i -= 16384;
  if (i < 16384){ int n = i / 128, k = i % 128; w3T[i] = f2bf1(W3[k*128 + n]); return; }
  i -= 16384;
  if (i < 65536){ int n = i / 128, k = i % 128; winT[i] = f2bf1(Win[k*512 + n]); return; }
  i -= 65536;
  if (i < 65536){ int n = i / 512, k = i % 512; woutT[i] = f2bf1(Wout[k*128 + n]); return; }
}

// ---------------- node_part = h_V @ W1[:128,:] + b1  (256 blocks, 32 rows) ----
__global__ __launch_bounds__(256,4) void np_kernel(
    const float* __restrict__ hV, const short* __restrict__ w1vT,
    const float* __restrict__ b1, float* __restrict__ npart)
{
  const int row0 = blockIdx.x * 32;
  const int tid = threadIdx.x, lane = tid & 63, wv = tid >> 6;
  __shared__ __attribute__((aligned(16))) short Xs[32][Hh + 8];

  const float4* src = (const float4*)(hV + (size_t)row0 * Hh);
  #pragma unroll
  for (int j = 0; j < 4; ++j){
    int idx = tid + 256*j;
    int r = idx >> 5, c4 = idx & 31;
    float4 v = src[idx];
    *(uint2*)&Xs[r][c4*4] = make_uint2(pk_bf16(v.x,v.y), pk_bf16(v.z,v.w));
  }
  __syncthreads();

  const int arow = lane & 15, kgrp = (lane >> 4) * 8;
  const int col0 = wv * 32, ccol = lane & 15, crow0 = (lane >> 4) * 4;

  f32x4 acc[2][2];
  #pragma unroll
  for (int m = 0; m < 2; ++m) for (int n = 0; n < 2; ++n) acc[m][n] = (f32x4){0.f,0.f,0.f,0.f};

  const short8v* Bw = (const short8v*)w1vT;
  #pragma unroll
  for (int ks = 0; ks < 4; ++ks){
    int kb = ks*32 + kgrp;
    short8v b0 = Bw[(col0 + arow)*16      + (kb >> 3)];
    short8v b1f = Bw[(col0 + 16 + arow)*16 + (kb >> 3)];
    #pragma unroll
    for (int m = 0; m < 2; ++m){
      short8v a = *(const short8v*)&Xs[m*16 + arow][kb];
      acc[m][0] = __builtin_amdgcn_mfma_f32_16x16x32_bf16(a, b0,  acc[m][0], 0,0,0);
      acc[m][1] = __builtin_amdgcn_mfma_f32_16x16x32_bf16(a, b1f, acc[m][1], 0,0,0);
    }
  }
  #pragma unroll
  for (int m = 0; m < 2; ++m) for (int n = 0; n < 2; ++n){
    int colg = col0 + n*16 + ccol;
    float bb = b1[colg];
    #pragma unroll
    for (int r = 0; r < 4; ++r)
      npart[(size_t)(row0 + m*16 + crow0 + r)*Hh + colg] = acc[m][n][r] + bb;
  }
}

// ---------------- edge MLP: K-chunked staging pipeline + collapsed G3 ----------
// (R12 verbatim — best measured structure.) One node per 4-wave block,
// 4 blocks/CU. Stage h_E in 3 chunks of 48x128 cols (6 float4/thread) so
// loads for chunk c+1 stay outstanding while G1 computes on chunk c
// (lgkm-only barriers). G3 collapsed: sum_k m_k(M2_k@W3+b3) =
// (sum_k m_k M2_k)@W3 + b3*sum(m); edge emits masked sum s per node.
__global__ __launch_bounds__(256,4) void edge_kernel(
    const float* __restrict__ hE,
    const float* __restrict__ maskA, const float* __restrict__ npart,
    const short* __restrict__ w1p, const short* __restrict__ w2p,
    const float* __restrict__ b2,
    float* __restrict__ sbuf, float* __restrict__ smaskbuf)
{
  const int node = blockIdx.x;
  const int tid = threadIdx.x, lane = tid & 63, wv = tid >> 6;   // wv 0..3
  const int e = lane & 15, q = lane >> 4;
  const int n0 = wv * 32;

  __shared__ __attribute__((aligned(16))) short Et[KN][NINc + 8];  // 48x392 = 37632B
  short (*M1)[136] = (short (*)[136])&Et[0][0];   // aliases Et after read-fence

  const float4* src = (const float4*)(hE + (size_t)node * (KN*NINc));
  float4 pf[6];

  // chunk c covers cols [c*128, c*128+128) of all 48 rows (1536 float4)
  auto LOADC = [&](int c){
    #pragma unroll
    for (int j = 0; j < 6; ++j){
      int idx = tid + 256*j;               // < 1536
      int r = idx >> 5, c4 = idx & 31;
      pf[j] = src[r*96 + c*32 + c4];
    }
  };
  auto STOREC = [&](int c){
    #pragma unroll
    for (int j = 0; j < 6; ++j){
      int idx = tid + 256*j;
      int r = idx >> 5, c4 = idx & 31;
      *(uint2*)&Et[r][c*128 + c4*4] =
        make_uint2(pk_bf16(pf[j].x, pf[j].y), pk_bf16(pf[j].z, pf[j].w));
    }
  };

  // loop-invariant loads (waited per-register at their uses)
  const float4 npv0 = *(const float4*)(npart + (size_t)node*Hh + n0 + 4*q);
  const float4 npv1 = *(const float4*)(npart + (size_t)node*Hh + n0 + 16 + 4*q);
  const float4 b2v0 = *(const float4*)(b2 + n0 + 4*q);
  const float4 b2v1 = *(const float4*)(b2 + n0 + 16 + 4*q);
  const float mk0 = maskA[node*KN + e];
  const float mk1 = maskA[node*KN + 16 + e];
  const float mk2 = maskA[node*KN + 32 + e];

  const f32x4 Z = (f32x4){0.f,0.f,0.f,0.f};
  f32x4 a00=Z, a10=Z, a20=Z, a01=Z, a11=Z, a21=Z;
  const short8v* B1 = (const short8v*)w1p;

  // ---- G1 over chunk c: ks in [4c, 4c+4) ----
  auto G1C = [&](int c){
    #pragma unroll
    for (int kk = 0; kk < 4; ++kk){
      int ks = c*4 + kk;
      short8v f0 = B1[((2*wv  )*12 + ks)*64 + lane];
      short8v f1 = B1[((2*wv+1)*12 + ks)*64 + lane];
      int kb = ks*32 + q*8;
      short8v t0 = *(const short8v*)&Et[e][kb];
      short8v t1 = *(const short8v*)&Et[16 + e][kb];
      short8v t2 = *(const short8v*)&Et[32 + e][kb];
      a00 = __builtin_amdgcn_mfma_f32_16x16x32_bf16(f0, t0, a00, 0,0,0);
      a10 = __builtin_amdgcn_mfma_f32_16x16x32_bf16(f0, t1, a10, 0,0,0);
      a20 = __builtin_amdgcn_mfma_f32_16x16x32_bf16(f0, t2, a20, 0,0,0);
      a01 = __builtin_amdgcn_mfma_f32_16x16x32_bf16(f1, t0, a01, 0,0,0);
      a11 = __builtin_amdgcn_mfma_f32_16x16x32_bf16(f1, t1, a11, 0,0,0);
      a21 = __builtin_amdgcn_mfma_f32_16x16x32_bf16(f1, t2, a21, 0,0,0);
    }
  };

  // ---- chunk-pipelined staging + G1 ----
  LOADC(0);
  STOREC(0);
  LOADC(1);          // outstanding across barrier + G1(0)
  bar_lds();         // chunk0 visible
  G1C(0);
  STOREC(1);         // per-register vmcnt waits (loads had G1(0) to land)
  LOADC(2);
  bar_lds();         // chunk1 visible
  G1C(1);
  STOREC(2);
  bar_lds();         // chunk2 visible
  G1C(2);
  bar_lds();         // READ-FENCE: all Et reads done -> M1 alias region free

  #define WR_M(ACC, ET, COLB, BV)  { short4 s;                      \
    s.x = f2bf1(gelu_f(ACC[0] + BV.x));                             \
    s.y = f2bf1(gelu_f(ACC[1] + BV.y));                             \
    s.z = f2bf1(gelu_f(ACC[2] + BV.z));                             \
    s.w = f2bf1(gelu_f(ACC[3] + BV.w));                             \
    *(short4*)&M1[16*ET + e][COLB + 4*q] = s; }

  WR_M(a00, 0, n0,      npv0)  WR_M(a10, 1, n0,      npv0)
  WR_M(a20, 2, n0,      npv0)  WR_M(a01, 0, n0 + 16, npv1)
  WR_M(a11, 1, n0 + 16, npv1)  WR_M(a21, 2, n0 + 16, npv1)
  #undef WR_M
  bar_lds();         // M1 visible

  // ---- G2 + collapsed-G3 epilogue ----
  {
    f32x4 c00=Z, c10=Z, c20=Z, c01=Z, c11=Z, c21=Z;
    const short8v* B2f = (const short8v*)w2p;
    #pragma unroll
    for (int ks = 0; ks < 4; ++ks){
      short8v f0 = B2f[((2*wv  )*4 + ks)*64 + lane];
      short8v f1 = B2f[((2*wv+1)*4 + ks)*64 + lane];
      int kb = ks*32 + q*8;
      short8v t0 = *(const short8v*)&M1[e][kb];
      short8v t1 = *(const short8v*)&M1[16 + e][kb];
      short8v t2 = *(const short8v*)&M1[32 + e][kb];
      c00 = __builtin_amdgcn_mfma_f32_16x16x32_bf16(f0, t0, c00, 0,0,0);
      c10 = __builtin_amdgcn_mfma_f32_16x16x32_bf16(f0, t1, c10, 0,0,0);
      c20 = __builtin_amdgcn_mfma_f32_16x16x32_bf16(f0, t2, c20, 0,0,0);
      c01 = __builtin_amdgcn_mfma_f32_16x16x32_bf16(f1, t0, c01, 0,0,0);
      c11 = __builtin_amdgcn_mfma_f32_16x16x32_bf16(f1, t1, c11, 0,0,0);
      c21 = __builtin_amdgcn_mfma_f32_16x16x32_bf16(f1, t2, c21, 0,0,0);
    }
    // s[col] = sum_e mask_e * gelu(M2pre[e][col] + b2[col]); butterfly over e
    float sv0[4], sv1[4];
    #pragma unroll
    for (int r = 0; r < 4; ++r){
      sv0[r] = gelu_f(c00[r] + b2v0[r])*mk0 + gelu_f(c10[r] + b2v0[r])*mk1
             + gelu_f(c20[r] + b2v0[r])*mk2;
      sv1[r] = gelu_f(c01[r] + b2v1[r])*mk0 + gelu_f(c11[r] + b2v1[r])*mk1
             + gelu_f(c21[r] + b2v1[r])*mk2;
    }
    float m3 = mk0 + mk1 + mk2;
    #pragma unroll
    for (int s = 1; s <= 8; s <<= 1){
      #pragma unroll
      for (int r = 0; r < 4; ++r){
        sv0[r] += __shfl_xor(sv0[r], s);
        sv1[r] += __shfl_xor(sv1[r], s);
      }
      m3 += __shfl_xor(m3, s);
    }
    if (e == 0){
      *(float4*)(sbuf + (size_t)node*Hh + n0 + 4*q) =
          make_float4(sv0[0], sv0[1], sv0[2], sv0[3]);
      *(float4*)(sbuf + (size_t)node*Hh + n0 + 16 + 4*q) =
          make_float4(sv1[0], sv1[1], sv1[2], sv1[3]);
    }
    if (tid == 0) smaskbuf[node] = m3;
  }
}

// ---------------- fused: h = hV + (S@W3 + b3*sm)/30 -> LN1 -> FFN -> LN2 -> mask ----
__global__ __launch_bounds__(256,2) void ffn2_kernel(
    const float* __restrict__ hV, const float* __restrict__ sbuf,
    const float* __restrict__ smaskbuf, const short* __restrict__ w3T,
    const float* __restrict__ b3,
    const float* __restrict__ ln1g, const float* __restrict__ ln1b,
    const short* __restrict__ winT, const float* __restrict__ bin,
    const short* __restrict__ woutT, const float* __restrict__ bout,
    const float* __restrict__ ln2g, const float* __restrict__ ln2b,
    const float* __restrict__ maskV, float* __restrict__ out)
{
  const int row0 = blockIdx.x * 32;
  const int tid = threadIdx.x, lane = tid & 63, wv = tid >> 6;
  __shared__ __attribute__((aligned(16))) short Xs[32][Hh + 8];
  __shared__ __attribute__((aligned(16))) float Rs[32][Hh + 4];
  __shared__ __attribute__((aligned(16))) short Hs[32][FFd + 8];
  __shared__ float smS[32];

  const int arow = lane & 15, kgrp = (lane >> 4) * 8;
  const int ccol = lane & 15, crow0 = (lane >> 4) * 4;

  // stage S -> Xs (bf16), smask
  {
    const float4* src = (const float4*)(sbuf + (size_t)row0 * Hh);
    #pragma unroll
    for (int j = 0; j < 4; ++j){
      int idx = tid + 256*j;
      int r = idx >> 5, c4 = idx & 31;
      float4 v = src[idx];
      *(uint2*)&Xs[r][c4*4] = make_uint2(pk_bf16(v.x,v.y), pk_bf16(v.z,v.w));
    }
    if (tid < 32) smS[tid] = smaskbuf[row0 + tid];
  }
  __syncthreads();

  // dh GEMM: Rs = hV + (Xs@W3 + b3*sm)/30
  {
    f32x4 acc[2][2];
    #pragma unroll
    for (int m = 0; m < 2; ++m) for (int n = 0; n < 2; ++n) acc[m][n] = (f32x4){0.f,0.f,0.f,0.f};
    const short8v* Bw = (const short8v*)w3T;
    const int col0 = wv * 32;
    #pragma unroll
    for (int ks = 0; ks < 4; ++ks){
      int kb = ks*32 + kgrp;
      short8v b0 = Bw[(col0 + arow)*16      + (kb >> 3)];
      short8v b1f = Bw[(col0 + 16 + arow)*16 + (kb >> 3)];
      #pragma unroll
      for (int m = 0; m < 2; ++m){
        short8v a = *(const short8v*)&Xs[m*16 + arow][kb];
        acc[m][0] = __builtin_amdgcn_mfma_f32_16x16x32_bf16(a, b0,  acc[m][0], 0,0,0);
        acc[m][1] = __builtin_amdgcn_mfma_f32_16x16x32_bf16(a, b1f, acc[m][1], 0,0,0);
      }
    }
    #pragma unroll
    for (int m = 0; m < 2; ++m) for (int n = 0; n < 2; ++n){
      int colg = col0 + n*16 + ccol;
      float bb = b3[colg];
      #pragma unroll
      for (int r = 0; r < 4; ++r){
        int rl = m*16 + crow0 + r;
        Rs[rl][colg] = hV[(size_t)(row0 + rl)*Hh + colg]
                     + (acc[m][n][r] + bb*smS[rl]) * (1.0f/30.0f);
      }
    }
  }
  __syncthreads();

  // LN1 in place on Rs; Xs = bf16(LN1); Rs keeps residual
  {
    int r = tid >> 3, cb = (tid & 7) * 16;
    float xv[16];
    #pragma unroll
    for (int j = 0; j < 16; ++j) xv[j] = Rs[r][cb + j];
    float sum = 0.f, sq = 0.f;
    #pragma unroll
    for (int j = 0; j < 16; ++j){ sum += xv[j]; sq += xv[j]*xv[j]; }
    #pragma unroll
    for (int d = 1; d < 8; d <<= 1){ sum += __shfl_xor(sum, d); sq += __shfl_xor(sq, d); }
    float mu = sum * (1.0f/128.0f);
    float var = sq * (1.0f/128.0f) - mu*mu;
    float rstd = rsqrtf(var + 1e-5f);
    #pragma unroll
    for (int j = 0; j < 16; ++j){
      int c = cb + j;
      float xn = (xv[j] - mu) * rstd * ln1g[c] + ln1b[c];
      Xs[r][c] = f2bf1(xn);
      Rs[r][c] = xn;          // residual
    }
  }
  __syncthreads();

  // GEMM-in: [32x128] @ WinT -> gelu -> Hs[32x512]
  {
    f32x4 acc[2][8];
    #pragma unroll
    for (int m = 0; m < 2; ++m) for (int n = 0; n < 8; ++n) acc[m][n] = (f32x4){0.f,0.f,0.f,0.f};
    const short8v* Bw = (const short8v*)winT;
    #pragma unroll
    for (int ks = 0; ks < 4; ++ks){
      int kb = ks*32 + kgrp;
      short8v a0 = *(const short8v*)&Xs[arow][kb];
      short8v a1 = *(const short8v*)&Xs[16 + arow][kb];
      #pragma unroll
      for (int n = 0; n < 8; ++n){
        short8v b = Bw[(wv*128 + n*16 + arow)*16 + (kb >> 3)];
        acc[0][n] = __builtin_amdgcn_mfma_f32_16x16x32_bf16(a0,b,acc[0][n],0,0,0);
        acc[1][n] = __builtin_amdgcn_mfma_f32_16x16x32_bf16(a1,b,acc[1][n],0,0,0);
      }
    }
    #pragma unroll
    for (int m = 0; m < 2; ++m) for (int n = 0; n < 8; ++n){
      int colg = wv*128 + n*16 + ccol;
      float bb = bin[colg];
      #pragma unroll
      for (int r = 0; r < 4; ++r)
        Hs[m*16 + crow0 + r][colg] = f2bf1(gelu_f(acc[m][n][r] + bb));
    }
  }
  __syncthreads();

  // GEMM-out: [32x512] @ WoutT -> + bout + resid -> Rs (pre-LN2)
  {
    f32x4 acc[2][2];
    #pragma unroll
    for (int m = 0; m < 2; ++m) for (int n = 0; n < 2; ++n) acc[m][n] = (f32x4){0.f,0.f,0.f,0.f};
    const short8v* Bw = (const short8v*)woutT;
    #pragma unroll
    for (int ks = 0; ks < 16; ++ks){
      int kb = ks*32 + kgrp;
      short8v a0 = *(const short8v*)&Hs[arow][kb];
      short8v a1 = *(const short8v*)&Hs[16 + arow][kb];
      short8v b0 = Bw[(wv*32 + arow)*64      + (kb >> 3)];
      short8v b1f = Bw[(wv*32 + 16 + arow)*64 + (kb >> 3)];
      acc[0][0] = __builtin_amdgcn_mfma_f32_16x16x32_bf16(a0,b0, acc[0][0],0,0,0);
      acc[1][0] = __builtin_amdgcn_mfma_f32_16x16x32_bf16(a1,b0, acc[1][0],0,0,0);
      acc[0][1] = __builtin_amdgcn_mfma_f32_16x16x32_bf16(a0,b1f,acc[0][1],0,0,0);
      acc[1][1] = __builtin_amdgcn_mfma_f32_16x16x32_bf16(a1,b1f,acc[1][1],0,0,0);
    }
    #pragma unroll
    for (int m = 0; m < 2; ++m) for (int n = 0; n < 2; ++n){
      int colg = wv*32 + n*16 + ccol;
      float bb = bout[colg];
      #pragma unroll
      for (int r = 0; r < 4; ++r){
        int rr = m*16 + crow0 + r;
        Rs[rr][colg] = Rs[rr][colg] + acc[m][n][r] + bb;
      }
    }
  }
  __syncthreads();

  // LN2 + mask + store
  {
    int r = tid >> 3, cb = (tid & 7) * 16;
    float xv[16];
    #pragma unroll
    for (int j = 0; j < 16; ++j) xv[j] = Rs[r][cb + j];
    float sum = 0.f, sq = 0.f;
    #pragma unroll
    for (int j = 0; j < 16; ++j){ sum += xv[j]; sq += xv[j]*xv[j]; }
    #pragma unroll
    for (int d = 1; d < 8; d <<= 1){ sum += __shfl_xor(sum, d); sq += __shfl_xor(sq, d); }
    float mu = sum * (1.0f/128.0f);
    float var = sq * (1.0f/128.0f) - mu*mu;
    float rstd = rsqrtf(var + 1e-5f);
    float mv = maskV[row0 + r];
    float* op = out + (size_t)(row0 + r)*Hh + cb;
    #pragma unroll
    for (int j = 0; j < 4; ++j){
      float4 o;
      o.x = ((xv[j*4+0] - mu)*rstd*ln2g[cb+j*4+0] + ln2b[cb+j*4+0]) * mv;
      o.y = ((xv[j*4+1] - mu)*rstd*ln2g[cb+j*4+1] + ln2b[cb+j*4+1]) * mv;
      o.z = ((xv[j*4+2] - mu)*rstd*ln2g[cb+j*4+2] + ln2b[cb+j*4+2]) * mv;
      o.w = ((xv[j*4+3] - mu)*rstd*ln2g[cb+j*4+3] + ln2b[cb+j*4+3]) * mv;
      ((float4*)op)[j] = o;
    }
  }
}

extern "C" void kernel_launch(void* const* d_in, const int* in_sizes, int n_in,
                              void* d_out, int out_size, void* d_ws, size_t ws_size,
                              hipStream_t stream)
{
  const float* hV    = (const float*)d_in[0];
  const float* hE    = (const float*)d_in[1];
  const float* maskV = (const float*)d_in[2];
  const float* maskA = (const float*)d_in[3];
  const float* W1w   = (const float*)d_in[4];
  const float* W1b   = (const float*)d_in[5];
  const float* W2w   = (const float*)d_in[6];
  const float* W2b   = (const float*)d_in[7];
  const float* W3w   = (const float*)d_in[8];
  const float* W3b   = (const float*)d_in[9];
  const float* Winw  = (const float*)d_in[10];
  const float* Winb  = (const float*)d_in[11];
  const float* Woutw = (const float*)d_in[12];
  const float* Woutb = (const float*)d_in[13];
  const float* l1g   = (const float*)d_in[14];
  const float* l1b   = (const float*)d_in[15];
  const float* l2g   = (const float*)d_in[16];
  const float* l2b   = (const float*)d_in[17];

  char* ws = (char*)d_ws;
  size_t off = 0;
  float* npart = (float*)(ws + off); off += (size_t)NNODE * Hh * 4;
  float* sbuf  = (float*)(ws + off); off += (size_t)NNODE * Hh * 4;
  float* smbuf = (float*)(ws + off); off += (size_t)NNODE * 4;
  short* w1vT  = (short*)(ws + off); off += 16384*2;
  short* w1p   = (short*)(ws + off); off += 49152*2;
  short* w2p   = (short*)(ws + off); off += 16384*2;
  short* w3T   = (short*)(ws + off); off += 16384*2;
  short* winT  = (short*)(ws + off); off += 65536*2;
  short* woutT = (short*)(ws + off); off += 65536*2;
  if (ws_size < off) return;

  prep_weights<<<896, 256, 0, stream>>>(W1w, W2w, W3w, Winw, Woutw,
                                        w1vT, w1p, w2p, w3T, winT, woutT);
  np_kernel<<<NNODE/32, 256, 0, stream>>>(hV, w1vT, W1b, npart);
  edge_kernel<<<NNODE, 256, 0, stream>>>(hE, maskA, npart,
                                         w1p, w2p, W2b, sbuf, smbuf);
  ffn2_kernel<<<NNODE/32, 256, 0, stream>>>(hV, sbuf, smbuf, w3T, W3b,
                                            l1g, l1b, winT, Winb, woutT, Woutb,
                                            l2g, l2b, maskV, (float*)d_out);
}